// Round 8
// baseline (254.544 us; speedup 1.0000x reference)
//
#include <hip/hip_runtime.h>
#include <hip/hip_bf16.h>
#include <math.h>

// Problem constants (from reference)
#define FEAT 128
#define HID 64
#define LAT 32
#define NG 64
#define MAXN 30
#define SCAN_CHUNK 512
#define NPART 8
// out layout: adj (30*30=900) | mu (64*32=2048) | logvar (2048)

typedef __hip_bfloat16 bf16;

__global__ void k_zero_w(int* p, int n) {   // zero n 4-byte words
    int i = blockIdx.x * blockDim.x + threadIdx.x;
    if (i < n) p[i] = 0;
}

// Partitioned in-degree histogram, direct global atomics: partition p =
// blockIdx&7 -> XCD p by round-robin dispatch; p owns dst range [base,lim)
// -> hist lines RMW'd by one XCD only, no cross-XCD line bouncing.
__global__ __launch_bounds__(256) void k_hist_part(const int* __restrict__ dst,
                                                   int* __restrict__ hist,
                                                   int N, int E) {
    int part = blockIdx.x & (NPART - 1);
    int psz0 = (N + NPART - 1) / NPART;
    int base = part * psz0;
    int lim = min(base + psz0, N);
    int bpp = gridDim.x >> 3;
    int bi = blockIdx.x >> 3;
    for (long e = (long)bi * 256 + threadIdx.x; e < E; e += (long)bpp * 256) {
        int d = dst[e];
        if (d >= base && d < lim) atomicAdd(&hist[d], 1);
    }
}

// block-level inclusive scan (Hillis-Steele), chunk = 512
__global__ __launch_bounds__(SCAN_CHUNK) void k_scan1(const int* __restrict__ hist,
                                                      int* __restrict__ incl,
                                                      int* __restrict__ bsum, int N) {
    __shared__ int buf[SCAN_CHUNK];
    int i = blockIdx.x * SCAN_CHUNK + threadIdx.x;
    int v = (i < N) ? hist[i] : 0;
    buf[threadIdx.x] = v;
    __syncthreads();
    for (int d = 1; d < SCAN_CHUNK; d <<= 1) {
        int t = (threadIdx.x >= d) ? buf[threadIdx.x - d] : 0;
        __syncthreads();
        buf[threadIdx.x] += t;
        __syncthreads();
    }
    if (i < N) incl[i] = buf[threadIdx.x];
    if (threadIdx.x == SCAN_CHUNK - 1) bsum[blockIdx.x] = buf[threadIdx.x];
}

// scan of block sums (single block) -> exclusive
__global__ __launch_bounds__(128) void k_scan_top(int* bsum, int nb) {
    __shared__ int buf[128];
    int v = (threadIdx.x < nb) ? bsum[threadIdx.x] : 0;
    buf[threadIdx.x] = v;
    __syncthreads();
    for (int d = 1; d < 128; d <<= 1) {
        int t = (threadIdx.x >= d) ? buf[threadIdx.x - d] : 0;
        __syncthreads();
        buf[threadIdx.x] += t;
        __syncthreads();
    }
    if (threadIdx.x < nb) bsum[threadIdx.x] = buf[threadIdx.x] - v;  // exclusive
}

// finalize: exclusive offsets, cursor copy, dinv = rsqrt(1 + indeg)
__global__ void k_scan_add(const int* __restrict__ hist, const int* __restrict__ incl,
                           const int* __restrict__ bsum, int* __restrict__ off,
                           int* __restrict__ cursor, float* __restrict__ dinv,
                           int N, int E) {
    int i = blockIdx.x * blockDim.x + threadIdx.x;
    if (i < N) {
        int h = hist[i];
        int o = incl[i] - h + bsum[i / SCAN_CHUNK];
        off[i] = o;
        cursor[i] = o;
        dinv[i] = rsqrtf(1.0f + (float)h);
    }
    if (i == 0) off[N] = E;
}

// Partitioned bucket-fill: CSR region written by one XCD only.
__global__ __launch_bounds__(256) void k_sortedges_part(const int* __restrict__ src,
                                                        const int* __restrict__ dst,
                                                        int* __restrict__ cursor,
                                                        int* __restrict__ ssrc,
                                                        int N, int E) {
    int part = blockIdx.x & (NPART - 1);
    int psz0 = (N + NPART - 1) / NPART;
    int base = part * psz0;
    int psize = min(psz0, N - base);
    int bpp = gridDim.x >> 3;
    int bi = blockIdx.x >> 3;
    for (long e = (long)bi * 256 + threadIdx.x; e < E; e += (long)bpp * 256) {
        int d = dst[e];
        int r = d - base;
        if ((unsigned)r < (unsigned)psize) {
            int pos = atomicAdd(&cursor[d], 1);
            ssrc[pos] = src[e];
        }
    }
}

// GEMM: hw = bf16(in @ W)  (N x K @ K x 64). One wave per row; W in LDS.
template <int K>
__global__ __launch_bounds__(256) void k_gemm(const float* __restrict__ in,
                                              const float* __restrict__ W,
                                              bf16* __restrict__ hw, int N) {
    __shared__ float Wl[K * 64];
    __shared__ float xr[4][K];
    int tid = threadIdx.x;
    for (int i = tid; i < K * 64; i += 256) Wl[i] = W[i];
    __syncthreads();
    int lane = tid & 63;
    int wv = tid >> 6;
    int stride = gridDim.x * 4;
    for (int row = blockIdx.x * 4 + wv; row < N; row += stride) {
        for (int k = lane; k < K; k += 64) xr[wv][k] = in[(long)row * K + k];
        float acc = 0.0f;
#pragma unroll
        for (int k = 0; k < K; ++k) acc += xr[wv][k] * Wl[k * 64 + lane];
        hw[(long)row * 64 + lane] = __float2bfloat16(acc);
    }
}

__device__ inline void red4(float4& a) {
    a.x += __shfl_xor(a.x, 16); a.y += __shfl_xor(a.y, 16);
    a.z += __shfl_xor(a.z, 16); a.w += __shfl_xor(a.w, 16);
    a.x += __shfl_xor(a.x, 32); a.y += __shfl_xor(a.y, 32);
    a.z += __shfl_xor(a.z, 32); a.w += __shfl_xor(a.w, 32);
}

// 4-edge vectorized gather core: lane = (edge sub, feature quad). One wave
// processes 4 edges per memory instruction (uint2 = 4 bf16 per lane,
// 512B/wave-instr). Returns row result in float4 (all lanes identical).
__device__ inline float4 gather_core(const bf16* __restrict__ hw,
                                     const int* __restrict__ ssrc,
                                     const float* __restrict__ dinv,
                                     int wid, int j0, int j1,
                                     float di, int sub, int q,
                                     const float* __restrict__ b) {
    float4 acc = make_float4(0.f, 0.f, 0.f, 0.f);
    for (int j = j0; j < j1; j += 4) {
        int jj = j + sub;
        int s = wid;
        float en = 0.0f;
        if (jj < j1) { s = ssrc[jj]; en = dinv[s] * di; }
        uint2 v = *reinterpret_cast<const uint2*>(hw + (((long)s << 6) + (q << 2)));
        acc.x += __uint_as_float((v.x & 0xFFFFu) << 16) * en;
        acc.y += __uint_as_float(v.x & 0xFFFF0000u) * en;
        acc.z += __uint_as_float((v.y & 0xFFFFu) << 16) * en;
        acc.w += __uint_as_float(v.y & 0xFFFF0000u) * en;
    }
    red4(acc);
    // self term + bias
    uint2 sv = *reinterpret_cast<const uint2*>(hw + (((long)wid << 6) + (q << 2)));
    float sn = di * di;
    float4 bq = *reinterpret_cast<const float4*>(b + (q << 2));
    acc.x += __uint_as_float((sv.x & 0xFFFFu) << 16) * sn + bq.x;
    acc.y += __uint_as_float(sv.x & 0xFFFF0000u) * sn + bq.y;
    acc.z += __uint_as_float((sv.y & 0xFFFFu) << 16) * sn + bq.z;
    acc.w += __uint_as_float(sv.y & 0xFFFF0000u) * sn + bq.w;
    return acc;
}

// Layer-1 fused: gather(hw1) -> relu -> h1 row (LDS, wave-private)
//               -> hw2 = bf16(h1 @ W2)   (W2 staged bf16 in LDS)
// h1 never touches global memory; k_gemm<64> launch eliminated.
__global__ __launch_bounds__(256) void k_gather_mm(const bf16* __restrict__ hw,
                                                   const int* __restrict__ ssrc,
                                                   const int* __restrict__ off,
                                                   const float* __restrict__ dinv,
                                                   const float* __restrict__ b1,
                                                   const float* __restrict__ W2,
                                                   bf16* __restrict__ hw2, int N) {
    __shared__ bf16 W2l[HID * HID];   // 8KB
    __shared__ float h1r[4][HID];     // 1KB, wave-private rows
    int tid = threadIdx.x;
    for (int i = tid; i < HID * HID; i += 256) W2l[i] = __float2bfloat16(W2[i]);
    __syncthreads();
    int wv = tid >> 6, lane = tid & 63;
    int wid = blockIdx.x * 4 + wv;
    if (wid >= N) return;  // after the only barrier
    int j0 = off[wid], j1 = off[wid + 1];
    float di = dinv[wid];
    int sub = lane >> 4, q = lane & 15;
    float4 r = gather_core(hw, ssrc, dinv, wid, j0, j1, di, sub, q, b1);
    // relu -> h1 row in LDS (lanes of sub-group 0 write; same-wave LDS
    // ordering is preserved by the compiler's conservative aliasing on h1r)
    r.x = fmaxf(r.x, 0.f); r.y = fmaxf(r.y, 0.f);
    r.z = fmaxf(r.z, 0.f); r.w = fmaxf(r.w, 0.f);
    if (sub == 0) *reinterpret_cast<float4*>(&h1r[wv][q << 2]) = r;
    // hw2[wid][lane] = sum_k h1[k] * W2[k][lane]
    float s2 = 0.0f;
#pragma unroll 16
    for (int k = 0; k < HID; ++k)
        s2 += h1r[wv][k] * __bfloat162float(W2l[k * 64 + lane]);
    hw2[((long)wid << 6) + lane] = __float2bfloat16(s2);
}

// Layer-2 gather: agg2 (f32) out, relu deferred to pool.
__global__ __launch_bounds__(256) void k_gather4(const bf16* __restrict__ hw,
                                                 const int* __restrict__ ssrc,
                                                 const int* __restrict__ off,
                                                 const float* __restrict__ dinv,
                                                 const float* __restrict__ b,
                                                 float* __restrict__ outb, int N) {
    int wv = threadIdx.x >> 6, lane = threadIdx.x & 63;
    int wid = blockIdx.x * 4 + wv;
    if (wid >= N) return;
    int j0 = off[wid], j1 = off[wid + 1];
    float di = dinv[wid];
    int sub = lane >> 4, q = lane & 15;
    float4 r = gather_core(hw, ssrc, dinv, wid, j0, j1, di, sub, q, b);
    if (sub == 0)
        *reinterpret_cast<float4*>(outb + (((long)wid << 6) + (q << 2))) = r;
}

// relu + mean-pool: batch is SORTED; each wave owns a contiguous node range,
// register-accumulates, flushes one atomicAdd per graph transition.
__global__ __launch_bounds__(256) void k_relu_pool(const float* __restrict__ agg,
                                                   const int* __restrict__ batch,
                                                   float* __restrict__ pooled,
                                                   float* __restrict__ counts,
                                                   int N, int rows_per_wave) {
    int wid = blockIdx.x * (blockDim.x >> 6) + (threadIdx.x >> 6);
    int lane = threadIdx.x & 63;
    int i0 = wid * rows_per_wave;
    if (i0 >= N) return;
    int i1 = min(i0 + rows_per_wave, N);
    int cur = batch[i0];
    float acc = 0.0f, cnt = 0.0f;
    for (int i = i0; i < i1; ++i) {
        int g = batch[i];
        if (g != cur) {
            atomicAdd(&pooled[cur * 64 + lane], acc);
            if (lane == 0) atomicAdd(&counts[cur], cnt);
            acc = 0.0f; cnt = 0.0f; cur = g;
        }
        acc += fmaxf(agg[(long)i * 64 + lane], 0.0f);
        cnt += 1.0f;
    }
    atomicAdd(&pooled[cur * 64 + lane], acc);
    if (lane == 0) atomicAdd(&counts[cur], cnt);
}

// mu / logvar heads with fused mean-divide -> out[900 + idx]
__global__ void k_heads(const float* __restrict__ pooled,
                        const float* __restrict__ counts,
                        const float* __restrict__ Wmu, const float* __restrict__ bmu,
                        const float* __restrict__ Wlv, const float* __restrict__ blv,
                        float* __restrict__ out) {
    int idx = blockIdx.x * blockDim.x + threadIdx.x;
    if (idx >= 2 * NG * LAT) return;
    int which = idx >> 11;          // 0: mu, 1: logvar
    int r = idx & (NG * LAT - 1);
    int g = r >> 5, l = r & 31;
    const float* W = which ? Wlv : Wmu;
    const float* b = which ? blv : bmu;
    float s = 0.0f;
#pragma unroll 8
    for (int h = 0; h < HID; ++h) s += pooled[g * 64 + h] * W[h * 32 + l];
    float c = fmaxf(counts[g], 1.0f);
    out[900 + idx] = s / c + b[l];
}

// Decoder stage 1: 30 blocks x 64 threads; parallelizes Wl2/We1 reads.
__global__ __launch_bounds__(64) void k_dec1(const float* __restrict__ Wl1,
                                             const float* __restrict__ bl1,
                                             const float* __restrict__ Wl2,
                                             const float* __restrict__ bl2,
                                             const float* __restrict__ We1,
                                             const float* __restrict__ out,
                                             float* __restrict__ hi,
                                             float* __restrict__ hj) {
    __shared__ float z0[LAT];
    __shared__ float hr[HID];
    __shared__ float em[HID];
    int tid = threadIdx.x;
    int n = blockIdx.x;
    if (tid < LAT) z0[tid] = out[900 + tid];  // mu row of graph 0
    __syncthreads();
    float s = bl1[tid];
#pragma unroll
    for (int l = 0; l < LAT; ++l) s += z0[l] * Wl1[l * HID + tid];
    hr[tid] = fmaxf(s, 0.0f);
    __syncthreads();
    float e = bl2[n * HID + tid];
#pragma unroll 8
    for (int h = 0; h < HID; ++h) e += hr[h] * Wl2[h * (HID * MAXN) + n * HID + tid];
    em[tid] = e;
    __syncthreads();
    float a = 0.0f, bb = 0.0f;
#pragma unroll 8
    for (int f = 0; f < HID; ++f) {
        float ev = em[f];
        a += ev * We1[f * HID + tid];
        bb += ev * We1[(HID + f) * HID + tid];
    }
    hi[n * HID + tid] = a;
    hj[n * HID + tid] = bb;
}

// Decoder stage 2: single block, adj from LDS-staged hi/hj (stride-65 pad).
__global__ __launch_bounds__(256) void k_dec2(const float* __restrict__ hi,
                                              const float* __restrict__ hj,
                                              const float* __restrict__ be1,
                                              const float* __restrict__ We2,
                                              const float* __restrict__ be2,
                                              float* __restrict__ out) {
    __shared__ float shi[MAXN * 65];
    __shared__ float shj[MAXN * 65];
    __shared__ float sbe[HID];
    __shared__ float sw[HID];
    int tid = threadIdx.x;
    for (int i = tid; i < MAXN * HID; i += 256) {
        int n = i >> 6, k = i & 63;
        shi[n * 65 + k] = hi[i];
        shj[n * 65 + k] = hj[i];
    }
    if (tid < HID) { sbe[tid] = be1[tid]; sw[tid] = We2[tid]; }
    __syncthreads();
    float bias2 = be2[0];
    for (int idx = tid; idx < MAXN * MAXN; idx += 256) {
        int i = idx / MAXN, j = idx % MAXN;
        if (i == j) { out[idx] = 0.0f; continue; }
        int a = i < j ? i : j;
        int b = i < j ? j : i;
        float s = bias2;
#pragma unroll 8
        for (int k = 0; k < HID; ++k)
            s += fmaxf(shi[a * 65 + k] + shj[b * 65 + k] + sbe[k], 0.0f) * sw[k];
        out[idx] = 1.0f / (1.0f + expf(-s));
    }
}

extern "C" void kernel_launch(void* const* d_in, const int* in_sizes, int n_in,
                              void* d_out, int out_size, void* d_ws, size_t ws_size,
                              hipStream_t stream) {
    const float* x = (const float*)d_in[0];
    const int* ei = (const int*)d_in[1];
    const int* batch = (const int*)d_in[2];
    const float* W1 = (const float*)d_in[4];
    const float* b1 = (const float*)d_in[5];
    const float* W2 = (const float*)d_in[6];
    const float* b2 = (const float*)d_in[7];
    const float* Wmu = (const float*)d_in[8];
    const float* bmu = (const float*)d_in[9];
    const float* Wlv = (const float*)d_in[10];
    const float* blv = (const float*)d_in[11];
    const float* Wl1 = (const float*)d_in[12];
    const float* bl1 = (const float*)d_in[13];
    const float* Wl2 = (const float*)d_in[14];
    const float* bl2 = (const float*)d_in[15];
    const float* We1 = (const float*)d_in[16];
    const float* be1 = (const float*)d_in[17];
    const float* We2 = (const float*)d_in[18];
    const float* be2 = (const float*)d_in[19];

    const int N = in_sizes[2];            // 50000
    const int E = in_sizes[1] / 2;        // 800000
    const int* src = ei;
    const int* dst = ei + E;

    // workspace carve-up, 256B aligned
    char* ws = (char*)d_ws;
    size_t off_b = 0;
    auto alloc = [&](size_t nbytes) {
        void* p = (void*)(ws + off_b);
        off_b = (off_b + nbytes + 255) & ~(size_t)255;
        return p;
    };
    float* dinv   = (float*)alloc((size_t)N * 4);
    float* bufA   = (float*)alloc((size_t)N * 64 * 4);        // agg2 (f32)
    bf16*  hwb1   = (bf16*)alloc((size_t)N * 64 * 2);         // hw1 (bf16)
    bf16*  hwb2   = (bf16*)alloc((size_t)N * 64 * 2);         // hw2 (bf16)
    // contiguous zero region: pooled | counts | hist
    float* pooled = (float*)alloc((NG * HID + NG + (size_t)N) * 4);
    float* counts = pooled + NG * HID;
    int*   hist   = (int*)(counts + NG);
    int*   incl   = (int*)alloc((size_t)N * 4);
    int*   bsum   = (int*)alloc(128 * 4);
    int*   offs   = (int*)alloc(((size_t)N + 1) * 4);
    int*   cursor = (int*)alloc((size_t)N * 4);
    int*   ssrc   = (int*)alloc((size_t)E * 4);
    float* dhi    = (float*)alloc(MAXN * HID * 4);
    float* dhj    = (float*)alloc(MAXN * HID * 4);

    float* out = (float*)d_out;
    const int nb_scan = (N + SCAN_CHUNK - 1) / SCAN_CHUNK;  // 98
    const int nzero = NG * HID + NG + N;

    // 0) one zero pass for pooled|counts|hist
    k_zero_w<<<(nzero + 255) / 256, 256, 0, stream>>>((int*)pooled, nzero);

    // 1) CSR build: hist -> scan -> offsets/dinv -> partitioned bucket fill
    k_hist_part<<<2048, 256, 0, stream>>>(dst, hist, N, E);
    k_scan1<<<nb_scan, SCAN_CHUNK, 0, stream>>>(hist, incl, bsum, N);
    k_scan_top<<<1, 128, 0, stream>>>(bsum, nb_scan);
    k_scan_add<<<(N + 255) / 256, 256, 0, stream>>>(hist, incl, bsum, offs, cursor, dinv, N, E);
    k_sortedges_part<<<1024, 256, 0, stream>>>(src, dst, cursor, ssrc, N, E);

    // 2) layer 1 GEMM: hw1 = bf16(x@W1)
    k_gemm<FEAT><<<2048, 256, 0, stream>>>(x, W1, hwb1, N);

    // 3) fused: gather1 + relu + gemm2 -> hw2
    k_gather_mm<<<(N + 3) / 4, 256, 0, stream>>>(hwb1, ssrc, offs, dinv, b1, W2, hwb2, N);

    // 4) gather2 -> agg2 (f32), relu deferred to pool
    k_gather4<<<(N + 3) / 4, 256, 0, stream>>>(hwb2, ssrc, offs, dinv, b2, bufA, N);

    // 5) relu + mean-pool (contiguous ranges, register accumulation)
    {
        const int waves = 2048;
        int rpw = (N + waves - 1) / waves;
        k_relu_pool<<<512, 256, 0, stream>>>(bufA, batch, pooled, counts, N, rpw);
    }

    // 6) mu / logvar (fused mean-divide) -> out[900:]
    k_heads<<<(2 * NG * LAT + 255) / 256, 256, 0, stream>>>(pooled, counts, Wmu, bmu, Wlv, blv, out);

    // 7) decoder -> out[0:900]
    k_dec1<<<MAXN, 64, 0, stream>>>(Wl1, bl1, Wl2, bl2, We1, out, dhi, dhj);
    k_dec2<<<1, 256, 0, stream>>>(dhi, dhj, be1, We2, be2, out);
}

// Round 9
// 229.583 us; speedup vs baseline: 1.1087x; 1.1087x over previous
//
#include <hip/hip_runtime.h>
#include <hip/hip_bf16.h>
#include <math.h>

// Problem constants (from reference)
#define FEAT 128
#define HID 64
#define LAT 32
#define NG 64
#define MAXN 30
#define SCAN_CHUNK 512
#define NPART 8
// out layout: adj (30*30=900) | mu (64*32=2048) | logvar (2048)

typedef __hip_bfloat16 bf16;

__global__ void k_zero_w(int* p, int n) {   // zero n 4-byte words
    int i = blockIdx.x * blockDim.x + threadIdx.x;
    if (i < n) p[i] = 0;
}

// Partitioned in-degree histogram, direct global atomics: partition p =
// blockIdx&7 -> XCD p by round-robin dispatch; p owns dst range [base,lim)
// -> hist lines RMW'd by one XCD only, no cross-XCD line bouncing.
__global__ __launch_bounds__(256) void k_hist_part(const int* __restrict__ dst,
                                                   int* __restrict__ hist,
                                                   int N, int E) {
    int part = blockIdx.x & (NPART - 1);
    int psz0 = (N + NPART - 1) / NPART;
    int base = part * psz0;
    int lim = min(base + psz0, N);
    int bpp = gridDim.x >> 3;
    int bi = blockIdx.x >> 3;
    for (long e = (long)bi * 256 + threadIdx.x; e < E; e += (long)bpp * 256) {
        int d = dst[e];
        if (d >= base && d < lim) atomicAdd(&hist[d], 1);
    }
}

// block-level inclusive scan (Hillis-Steele), chunk = 512
__global__ __launch_bounds__(SCAN_CHUNK) void k_scan1(const int* __restrict__ hist,
                                                      int* __restrict__ incl,
                                                      int* __restrict__ bsum, int N) {
    __shared__ int buf[SCAN_CHUNK];
    int i = blockIdx.x * SCAN_CHUNK + threadIdx.x;
    int v = (i < N) ? hist[i] : 0;
    buf[threadIdx.x] = v;
    __syncthreads();
    for (int d = 1; d < SCAN_CHUNK; d <<= 1) {
        int t = (threadIdx.x >= d) ? buf[threadIdx.x - d] : 0;
        __syncthreads();
        buf[threadIdx.x] += t;
        __syncthreads();
    }
    if (i < N) incl[i] = buf[threadIdx.x];
    if (threadIdx.x == SCAN_CHUNK - 1) bsum[blockIdx.x] = buf[threadIdx.x];
}

// scan of block sums (single block) -> exclusive
__global__ __launch_bounds__(128) void k_scan_top(int* bsum, int nb) {
    __shared__ int buf[128];
    int v = (threadIdx.x < nb) ? bsum[threadIdx.x] : 0;
    buf[threadIdx.x] = v;
    __syncthreads();
    for (int d = 1; d < 128; d <<= 1) {
        int t = (threadIdx.x >= d) ? buf[threadIdx.x - d] : 0;
        __syncthreads();
        buf[threadIdx.x] += t;
        __syncthreads();
    }
    if (threadIdx.x < nb) bsum[threadIdx.x] = buf[threadIdx.x] - v;  // exclusive
}

// finalize: exclusive offsets, cursor copy, dinv = rsqrt(1 + indeg)
__global__ void k_scan_add(const int* __restrict__ hist, const int* __restrict__ incl,
                           const int* __restrict__ bsum, int* __restrict__ off,
                           int* __restrict__ cursor, float* __restrict__ dinv,
                           int N, int E) {
    int i = blockIdx.x * blockDim.x + threadIdx.x;
    if (i < N) {
        int h = hist[i];
        int o = incl[i] - h + bsum[i / SCAN_CHUNK];
        off[i] = o;
        cursor[i] = o;
        dinv[i] = rsqrtf(1.0f + (float)h);
    }
    if (i == 0) off[N] = E;
}

// Partitioned bucket-fill: CSR region written by one XCD only.
__global__ __launch_bounds__(256) void k_sortedges_part(const int* __restrict__ src,
                                                        const int* __restrict__ dst,
                                                        int* __restrict__ cursor,
                                                        int* __restrict__ ssrc,
                                                        int N, int E) {
    int part = blockIdx.x & (NPART - 1);
    int psz0 = (N + NPART - 1) / NPART;
    int base = part * psz0;
    int psize = min(psz0, N - base);
    int bpp = gridDim.x >> 3;
    int bi = blockIdx.x >> 3;
    for (long e = (long)bi * 256 + threadIdx.x; e < E; e += (long)bpp * 256) {
        int d = dst[e];
        int r = d - base;
        if ((unsigned)r < (unsigned)psize) {
            int pos = atomicAdd(&cursor[d], 1);
            ssrc[pos] = src[e];
        }
    }
}

// GEMM: hw = bf16(in @ W)  (N x K @ K x 64). One wave per row; W in LDS.
template <int K>
__global__ __launch_bounds__(256) void k_gemm(const float* __restrict__ in,
                                              const float* __restrict__ W,
                                              bf16* __restrict__ hw, int N) {
    __shared__ float Wl[K * 64];
    __shared__ float xr[4][K];
    int tid = threadIdx.x;
    for (int i = tid; i < K * 64; i += 256) Wl[i] = W[i];
    __syncthreads();
    int lane = tid & 63;
    int wv = tid >> 6;
    int stride = gridDim.x * 4;
    for (int row = blockIdx.x * 4 + wv; row < N; row += stride) {
        for (int k = lane; k < K; k += 64) xr[wv][k] = in[(long)row * K + k];
        float acc = 0.0f;
#pragma unroll
        for (int k = 0; k < K; ++k) acc += xr[wv][k] * Wl[k * 64 + lane];
        hw[(long)row * 64 + lane] = __float2bfloat16(acc);
    }
}

__device__ inline void red4(float4& a) {
    a.x += __shfl_xor(a.x, 16); a.y += __shfl_xor(a.y, 16);
    a.z += __shfl_xor(a.z, 16); a.w += __shfl_xor(a.w, 16);
    a.x += __shfl_xor(a.x, 32); a.y += __shfl_xor(a.y, 32);
    a.z += __shfl_xor(a.z, 32); a.w += __shfl_xor(a.w, 32);
}

#define ACC4(v, en)                                              \
    acc.x += __uint_as_float(((v).x & 0xFFFFu) << 16) * (en);    \
    acc.y += __uint_as_float((v).x & 0xFFFF0000u) * (en);        \
    acc.z += __uint_as_float(((v).y & 0xFFFFu) << 16) * (en);    \
    acc.w += __uint_as_float((v).y & 0xFFFF0000u) * (en);

// Latency-optimized gather core.
// Phase 1 (per <=64-edge chunk): all 64 lanes load ssrc (coalesced) and
// dinv[s] (parallel scattered) -- the two chain links are paid ONCE, wave-wide.
// Phase 2: s/en come from __shfl (register-only); the row gather is the only
// memory op, 2x unrolled (8 edges, 2 independent 512B loads in flight).
__device__ inline float4 gather_core(const bf16* __restrict__ hw,
                                     const int* __restrict__ ssrc,
                                     const float* __restrict__ dinv,
                                     int wid, int j0, int j1,
                                     float di, int lane,
                                     const float* __restrict__ b) {
    int sub = lane >> 4, q = lane & 15;
    float4 acc = make_float4(0.f, 0.f, 0.f, 0.f);
    for (int base = j0; base < j1; base += 64) {
        int cnt = min(64, j1 - base);
        int s_r = wid;
        float en_r = 0.0f;
        if (lane < cnt) { s_r = ssrc[base + lane]; en_r = dinv[s_r] * di; }
        int j = 0;
        for (; j + 8 <= cnt; j += 8) {
            int sa = __shfl(s_r, j + sub);
            int sb = __shfl(s_r, j + 4 + sub);
            float ena = __shfl(en_r, j + sub);
            float enb = __shfl(en_r, j + 4 + sub);
            uint2 va = *reinterpret_cast<const uint2*>(hw + (((long)sa << 6) + (q << 2)));
            uint2 vb = *reinterpret_cast<const uint2*>(hw + (((long)sb << 6) + (q << 2)));
            ACC4(va, ena);
            ACC4(vb, enb);
        }
        for (; j < cnt; j += 4) {
            int e = j + sub;
            int s = __shfl(s_r, e);
            float en = __shfl(en_r, e);
            if (e >= cnt) { s = wid; en = 0.0f; }
            uint2 v = *reinterpret_cast<const uint2*>(hw + (((long)s << 6) + (q << 2)));
            ACC4(v, en);
        }
    }
    red4(acc);
    // self term + bias
    uint2 sv = *reinterpret_cast<const uint2*>(hw + (((long)wid << 6) + (q << 2)));
    float sn = di * di;
    float4 bq = *reinterpret_cast<const float4*>(b + (q << 2));
    acc.x += __uint_as_float((sv.x & 0xFFFFu) << 16) * sn + bq.x;
    acc.y += __uint_as_float(sv.x & 0xFFFF0000u) * sn + bq.y;
    acc.z += __uint_as_float((sv.y & 0xFFFFu) << 16) * sn + bq.z;
    acc.w += __uint_as_float(sv.y & 0xFFFF0000u) * sn + bq.w;
    return acc;
}

// Layer-1 fused: gather(hw1) -> relu -> h1 row (LDS, wave-private)
//               -> hw2 = bf16(h1 @ W2)   (W2 staged bf16 in LDS)
// h1 never touches global memory; k_gemm<64> launch eliminated.
__global__ __launch_bounds__(256) void k_gather_mm(const bf16* __restrict__ hw,
                                                   const int* __restrict__ ssrc,
                                                   const int* __restrict__ off,
                                                   const float* __restrict__ dinv,
                                                   const float* __restrict__ b1,
                                                   const float* __restrict__ W2,
                                                   bf16* __restrict__ hw2, int N) {
    __shared__ bf16 W2l[HID * HID];   // 8KB
    __shared__ float h1r[4][HID];     // 1KB, wave-private rows
    int tid = threadIdx.x;
    for (int i = tid; i < HID * HID; i += 256) W2l[i] = __float2bfloat16(W2[i]);
    __syncthreads();
    int wv = tid >> 6, lane = tid & 63;
    int wid = blockIdx.x * 4 + wv;
    if (wid >= N) return;  // after the only barrier
    int j0 = off[wid], j1 = off[wid + 1];
    float di = dinv[wid];
    float4 r = gather_core(hw, ssrc, dinv, wid, j0, j1, di, lane, b1);
    r.x = fmaxf(r.x, 0.f); r.y = fmaxf(r.y, 0.f);
    r.z = fmaxf(r.z, 0.f); r.w = fmaxf(r.w, 0.f);
    if ((lane >> 4) == 0) *reinterpret_cast<float4*>(&h1r[wv][(lane & 15) << 2]) = r;
    // hw2[wid][lane] = sum_k h1[k] * W2[k][lane]
    float s2 = 0.0f;
#pragma unroll 16
    for (int k = 0; k < HID; ++k)
        s2 += h1r[wv][k] * __bfloat162float(W2l[k * 64 + lane]);
    hw2[((long)wid << 6) + lane] = __float2bfloat16(s2);
}

// Layer-2 gather: agg2 (f32) out, relu deferred to pool.
__global__ __launch_bounds__(256) void k_gather4(const bf16* __restrict__ hw,
                                                 const int* __restrict__ ssrc,
                                                 const int* __restrict__ off,
                                                 const float* __restrict__ dinv,
                                                 const float* __restrict__ b,
                                                 float* __restrict__ outb, int N) {
    int wv = threadIdx.x >> 6, lane = threadIdx.x & 63;
    int wid = blockIdx.x * 4 + wv;
    if (wid >= N) return;
    int j0 = off[wid], j1 = off[wid + 1];
    float di = dinv[wid];
    float4 r = gather_core(hw, ssrc, dinv, wid, j0, j1, di, lane, b);
    if ((lane >> 4) == 0)
        *reinterpret_cast<float4*>(outb + (((long)wid << 6) + ((lane & 15) << 2))) = r;
}

// relu + mean-pool: batch is SORTED; each wave owns a contiguous node range,
// register-accumulates, flushes one atomicAdd per graph transition.
__global__ __launch_bounds__(256) void k_relu_pool(const float* __restrict__ agg,
                                                   const int* __restrict__ batch,
                                                   float* __restrict__ pooled,
                                                   float* __restrict__ counts,
                                                   int N, int rows_per_wave) {
    int wid = blockIdx.x * (blockDim.x >> 6) + (threadIdx.x >> 6);
    int lane = threadIdx.x & 63;
    int i0 = wid * rows_per_wave;
    if (i0 >= N) return;
    int i1 = min(i0 + rows_per_wave, N);
    int cur = batch[i0];
    float acc = 0.0f, cnt = 0.0f;
    for (int i = i0; i < i1; ++i) {
        int g = batch[i];
        if (g != cur) {
            atomicAdd(&pooled[cur * 64 + lane], acc);
            if (lane == 0) atomicAdd(&counts[cur], cnt);
            acc = 0.0f; cnt = 0.0f; cur = g;
        }
        acc += fmaxf(agg[(long)i * 64 + lane], 0.0f);
        cnt += 1.0f;
    }
    atomicAdd(&pooled[cur * 64 + lane], acc);
    if (lane == 0) atomicAdd(&counts[cur], cnt);
}

// mu / logvar heads with fused mean-divide -> out[900 + idx]
__global__ void k_heads(const float* __restrict__ pooled,
                        const float* __restrict__ counts,
                        const float* __restrict__ Wmu, const float* __restrict__ bmu,
                        const float* __restrict__ Wlv, const float* __restrict__ blv,
                        float* __restrict__ out) {
    int idx = blockIdx.x * blockDim.x + threadIdx.x;
    if (idx >= 2 * NG * LAT) return;
    int which = idx >> 11;          // 0: mu, 1: logvar
    int r = idx & (NG * LAT - 1);
    int g = r >> 5, l = r & 31;
    const float* W = which ? Wlv : Wmu;
    const float* b = which ? blv : bmu;
    float s = 0.0f;
#pragma unroll 8
    for (int h = 0; h < HID; ++h) s += pooled[g * 64 + h] * W[h * 32 + l];
    float c = fmaxf(counts[g], 1.0f);
    out[900 + idx] = s / c + b[l];
}

// Decoder stage 1: 30 blocks x 64 threads; parallelizes Wl2/We1 reads.
__global__ __launch_bounds__(64) void k_dec1(const float* __restrict__ Wl1,
                                             const float* __restrict__ bl1,
                                             const float* __restrict__ Wl2,
                                             const float* __restrict__ bl2,
                                             const float* __restrict__ We1,
                                             const float* __restrict__ out,
                                             float* __restrict__ hi,
                                             float* __restrict__ hj) {
    __shared__ float z0[LAT];
    __shared__ float hr[HID];
    __shared__ float em[HID];
    int tid = threadIdx.x;
    int n = blockIdx.x;
    if (tid < LAT) z0[tid] = out[900 + tid];  // mu row of graph 0
    __syncthreads();
    float s = bl1[tid];
#pragma unroll
    for (int l = 0; l < LAT; ++l) s += z0[l] * Wl1[l * HID + tid];
    hr[tid] = fmaxf(s, 0.0f);
    __syncthreads();
    float e = bl2[n * HID + tid];
#pragma unroll 8
    for (int h = 0; h < HID; ++h) e += hr[h] * Wl2[h * (HID * MAXN) + n * HID + tid];
    em[tid] = e;
    __syncthreads();
    float a = 0.0f, bb = 0.0f;
#pragma unroll 8
    for (int f = 0; f < HID; ++f) {
        float ev = em[f];
        a += ev * We1[f * HID + tid];
        bb += ev * We1[(HID + f) * HID + tid];
    }
    hi[n * HID + tid] = a;
    hj[n * HID + tid] = bb;
}

// Decoder stage 2: single block, adj from LDS-staged hi/hj (stride-65 pad).
__global__ __launch_bounds__(256) void k_dec2(const float* __restrict__ hi,
                                              const float* __restrict__ hj,
                                              const float* __restrict__ be1,
                                              const float* __restrict__ We2,
                                              const float* __restrict__ be2,
                                              float* __restrict__ out) {
    __shared__ float shi[MAXN * 65];
    __shared__ float shj[MAXN * 65];
    __shared__ float sbe[HID];
    __shared__ float sw[HID];
    int tid = threadIdx.x;
    for (int i = tid; i < MAXN * HID; i += 256) {
        int n = i >> 6, k = i & 63;
        shi[n * 65 + k] = hi[i];
        shj[n * 65 + k] = hj[i];
    }
    if (tid < HID) { sbe[tid] = be1[tid]; sw[tid] = We2[tid]; }
    __syncthreads();
    float bias2 = be2[0];
    for (int idx = tid; idx < MAXN * MAXN; idx += 256) {
        int i = idx / MAXN, j = idx % MAXN;
        if (i == j) { out[idx] = 0.0f; continue; }
        int a = i < j ? i : j;
        int b = i < j ? j : i;
        float s = bias2;
#pragma unroll 8
        for (int k = 0; k < HID; ++k)
            s += fmaxf(shi[a * 65 + k] + shj[b * 65 + k] + sbe[k], 0.0f) * sw[k];
        out[idx] = 1.0f / (1.0f + expf(-s));
    }
}

extern "C" void kernel_launch(void* const* d_in, const int* in_sizes, int n_in,
                              void* d_out, int out_size, void* d_ws, size_t ws_size,
                              hipStream_t stream) {
    const float* x = (const float*)d_in[0];
    const int* ei = (const int*)d_in[1];
    const int* batch = (const int*)d_in[2];
    const float* W1 = (const float*)d_in[4];
    const float* b1 = (const float*)d_in[5];
    const float* W2 = (const float*)d_in[6];
    const float* b2 = (const float*)d_in[7];
    const float* Wmu = (const float*)d_in[8];
    const float* bmu = (const float*)d_in[9];
    const float* Wlv = (const float*)d_in[10];
    const float* blv = (const float*)d_in[11];
    const float* Wl1 = (const float*)d_in[12];
    const float* bl1 = (const float*)d_in[13];
    const float* Wl2 = (const float*)d_in[14];
    const float* bl2 = (const float*)d_in[15];
    const float* We1 = (const float*)d_in[16];
    const float* be1 = (const float*)d_in[17];
    const float* We2 = (const float*)d_in[18];
    const float* be2 = (const float*)d_in[19];

    const int N = in_sizes[2];            // 50000
    const int E = in_sizes[1] / 2;        // 800000
    const int* src = ei;
    const int* dst = ei + E;

    // workspace carve-up, 256B aligned
    char* ws = (char*)d_ws;
    size_t off_b = 0;
    auto alloc = [&](size_t nbytes) {
        void* p = (void*)(ws + off_b);
        off_b = (off_b + nbytes + 255) & ~(size_t)255;
        return p;
    };
    float* dinv   = (float*)alloc((size_t)N * 4);
    float* bufA   = (float*)alloc((size_t)N * 64 * 4);        // agg2 (f32)
    bf16*  hwb1   = (bf16*)alloc((size_t)N * 64 * 2);         // hw1 (bf16)
    bf16*  hwb2   = (bf16*)alloc((size_t)N * 64 * 2);         // hw2 (bf16)
    // contiguous zero region: pooled | counts | hist
    float* pooled = (float*)alloc((NG * HID + NG + (size_t)N) * 4);
    float* counts = pooled + NG * HID;
    int*   hist   = (int*)(counts + NG);
    int*   incl   = (int*)alloc((size_t)N * 4);
    int*   bsum   = (int*)alloc(128 * 4);
    int*   offs   = (int*)alloc(((size_t)N + 1) * 4);
    int*   cursor = (int*)alloc((size_t)N * 4);
    int*   ssrc   = (int*)alloc((size_t)E * 4);
    float* dhi    = (float*)alloc(MAXN * HID * 4);
    float* dhj    = (float*)alloc(MAXN * HID * 4);

    float* out = (float*)d_out;
    const int nb_scan = (N + SCAN_CHUNK - 1) / SCAN_CHUNK;  // 98
    const int nzero = NG * HID + NG + N;

    // 0) one zero pass for pooled|counts|hist
    k_zero_w<<<(nzero + 255) / 256, 256, 0, stream>>>((int*)pooled, nzero);

    // 1) CSR build: hist -> scan -> offsets/dinv -> partitioned bucket fill
    k_hist_part<<<2048, 256, 0, stream>>>(dst, hist, N, E);
    k_scan1<<<nb_scan, SCAN_CHUNK, 0, stream>>>(hist, incl, bsum, N);
    k_scan_top<<<1, 128, 0, stream>>>(bsum, nb_scan);
    k_scan_add<<<(N + 255) / 256, 256, 0, stream>>>(hist, incl, bsum, offs, cursor, dinv, N, E);
    k_sortedges_part<<<1024, 256, 0, stream>>>(src, dst, cursor, ssrc, N, E);

    // 2) layer 1 GEMM: hw1 = bf16(x@W1)
    k_gemm<FEAT><<<2048, 256, 0, stream>>>(x, W1, hwb1, N);

    // 3) fused: gather1 + relu + gemm2 -> hw2
    k_gather_mm<<<(N + 3) / 4, 256, 0, stream>>>(hwb1, ssrc, offs, dinv, b1, W2, hwb2, N);

    // 4) gather2 -> agg2 (f32), relu deferred to pool
    k_gather4<<<(N + 3) / 4, 256, 0, stream>>>(hwb2, ssrc, offs, dinv, b2, bufA, N);

    // 5) relu + mean-pool (contiguous ranges, register accumulation)
    {
        const int waves = 2048;
        int rpw = (N + waves - 1) / waves;
        k_relu_pool<<<512, 256, 0, stream>>>(bufA, batch, pooled, counts, N, rpw);
    }

    // 6) mu / logvar (fused mean-divide) -> out[900:]
    k_heads<<<(2 * NG * LAT + 255) / 256, 256, 0, stream>>>(pooled, counts, Wmu, bmu, Wlv, blv, out);

    // 7) decoder -> out[0:900]
    k_dec1<<<MAXN, 64, 0, stream>>>(Wl1, bl1, Wl2, bl2, We1, out, dhi, dhj);
    k_dec2<<<1, 256, 0, stream>>>(dhi, dhj, be1, We2, be2, out);
}

// Round 10
// 213.835 us; speedup vs baseline: 1.1904x; 1.0736x over previous
//
#include <hip/hip_runtime.h>
#include <hip/hip_bf16.h>
#include <math.h>

// Problem constants (from reference)
#define FEAT 128
#define HID 64
#define LAT 32
#define NG 64
#define MAXN 30
#define SCAN_CHUNK 512
#define NPART 8
// out layout: adj (30*30=900) | mu (64*32=2048) | logvar (2048)

typedef __hip_bfloat16 bf16;
typedef short bf16x8 __attribute__((ext_vector_type(8)));
typedef float f32x4 __attribute__((ext_vector_type(4)));

__global__ void k_zero_w(int* p, int n) {   // zero n 4-byte words
    int i = blockIdx.x * blockDim.x + threadIdx.x;
    if (i < n) p[i] = 0;
}

// Partitioned in-degree histogram, direct global atomics: partition p =
// blockIdx&7 -> XCD p by round-robin dispatch; p owns dst range [base,lim)
// -> hist lines RMW'd by one XCD only, no cross-XCD line bouncing.
__global__ __launch_bounds__(256) void k_hist_part(const int* __restrict__ dst,
                                                   int* __restrict__ hist,
                                                   int N, int E) {
    int part = blockIdx.x & (NPART - 1);
    int psz0 = (N + NPART - 1) / NPART;
    int base = part * psz0;
    int lim = min(base + psz0, N);
    int bpp = gridDim.x >> 3;
    int bi = blockIdx.x >> 3;
    for (long e = (long)bi * 256 + threadIdx.x; e < E; e += (long)bpp * 256) {
        int d = dst[e];
        if (d >= base && d < lim) atomicAdd(&hist[d], 1);
    }
}

// block-level inclusive scan (Hillis-Steele), chunk = 512
__global__ __launch_bounds__(SCAN_CHUNK) void k_scan1(const int* __restrict__ hist,
                                                      int* __restrict__ incl,
                                                      int* __restrict__ bsum, int N) {
    __shared__ int buf[SCAN_CHUNK];
    int i = blockIdx.x * SCAN_CHUNK + threadIdx.x;
    int v = (i < N) ? hist[i] : 0;
    buf[threadIdx.x] = v;
    __syncthreads();
    for (int d = 1; d < SCAN_CHUNK; d <<= 1) {
        int t = (threadIdx.x >= d) ? buf[threadIdx.x - d] : 0;
        __syncthreads();
        buf[threadIdx.x] += t;
        __syncthreads();
    }
    if (i < N) incl[i] = buf[threadIdx.x];
    if (threadIdx.x == SCAN_CHUNK - 1) bsum[blockIdx.x] = buf[threadIdx.x];
}

// scan of block sums (single block) -> exclusive
__global__ __launch_bounds__(128) void k_scan_top(int* bsum, int nb) {
    __shared__ int buf[128];
    int v = (threadIdx.x < nb) ? bsum[threadIdx.x] : 0;
    buf[threadIdx.x] = v;
    __syncthreads();
    for (int d = 1; d < 128; d <<= 1) {
        int t = (threadIdx.x >= d) ? buf[threadIdx.x - d] : 0;
        __syncthreads();
        buf[threadIdx.x] += t;
        __syncthreads();
    }
    if (threadIdx.x < nb) bsum[threadIdx.x] = buf[threadIdx.x] - v;  // exclusive
}

// finalize: exclusive offsets, cursor copy, dinv = rsqrt(1 + indeg)
__global__ void k_scan_add(const int* __restrict__ hist, const int* __restrict__ incl,
                           const int* __restrict__ bsum, int* __restrict__ off,
                           int* __restrict__ cursor, float* __restrict__ dinv,
                           int N, int E) {
    int i = blockIdx.x * blockDim.x + threadIdx.x;
    if (i < N) {
        int h = hist[i];
        int o = incl[i] - h + bsum[i / SCAN_CHUNK];
        off[i] = o;
        cursor[i] = o;
        dinv[i] = rsqrtf(1.0f + (float)h);
    }
    if (i == 0) off[N] = E;
}

// Partitioned bucket-fill: CSR region written by one XCD only.
__global__ __launch_bounds__(256) void k_sortedges_part(const int* __restrict__ src,
                                                        const int* __restrict__ dst,
                                                        int* __restrict__ cursor,
                                                        int* __restrict__ ssrc,
                                                        int N, int E) {
    int part = blockIdx.x & (NPART - 1);
    int psz0 = (N + NPART - 1) / NPART;
    int base = part * psz0;
    int psize = min(psz0, N - base);
    int bpp = gridDim.x >> 3;
    int bi = blockIdx.x >> 3;
    for (long e = (long)bi * 256 + threadIdx.x; e < E; e += (long)bpp * 256) {
        int d = dst[e];
        int r = d - base;
        if ((unsigned)r < (unsigned)psize) {
            int pos = atomicAdd(&cursor[d], 1);
            ssrc[pos] = src[e];
        }
    }
}

// GEMM: hw = bf16(in @ W)  (N x K @ K x 64). One wave per row; W in LDS.
template <int K>
__global__ __launch_bounds__(256) void k_gemm(const float* __restrict__ in,
                                              const float* __restrict__ W,
                                              bf16* __restrict__ hw, int N) {
    __shared__ float Wl[K * 64];
    __shared__ float xr[4][K];
    int tid = threadIdx.x;
    for (int i = tid; i < K * 64; i += 256) Wl[i] = W[i];
    __syncthreads();
    int lane = tid & 63;
    int wv = tid >> 6;
    int stride = gridDim.x * 4;
    for (int row = blockIdx.x * 4 + wv; row < N; row += stride) {
        for (int k = lane; k < K; k += 64) xr[wv][k] = in[(long)row * K + k];
        float acc = 0.0f;
#pragma unroll
        for (int k = 0; k < K; ++k) acc += xr[wv][k] * Wl[k * 64 + lane];
        hw[(long)row * 64 + lane] = __float2bfloat16(acc);
    }
}

__device__ inline void red4(float4& a) {
    a.x += __shfl_xor(a.x, 16); a.y += __shfl_xor(a.y, 16);
    a.z += __shfl_xor(a.z, 16); a.w += __shfl_xor(a.w, 16);
    a.x += __shfl_xor(a.x, 32); a.y += __shfl_xor(a.y, 32);
    a.z += __shfl_xor(a.z, 32); a.w += __shfl_xor(a.w, 32);
}

#define ACC4(v, en)                                              \
    acc.x += __uint_as_float(((v).x & 0xFFFFu) << 16) * (en);    \
    acc.y += __uint_as_float((v).x & 0xFFFF0000u) * (en);        \
    acc.z += __uint_as_float(((v).y & 0xFFFFu) << 16) * (en);    \
    acc.w += __uint_as_float((v).y & 0xFFFF0000u) * (en);

// Latency-optimized gather core (see R9): per 64-edge chunk, all lanes load
// ssrc+dinv once (coalesced/parallel); inner loop gets s/en via shfl so the
// row gather is the only memory op, 2x unrolled.
__device__ inline float4 gather_core(const bf16* __restrict__ hw,
                                     const int* __restrict__ ssrc,
                                     const float* __restrict__ dinv,
                                     int wid, int j0, int j1,
                                     float di, int lane,
                                     const float* __restrict__ b) {
    int sub = lane >> 4, q = lane & 15;
    float4 acc = make_float4(0.f, 0.f, 0.f, 0.f);
    for (int base = j0; base < j1; base += 64) {
        int cnt = min(64, j1 - base);
        int s_r = wid;
        float en_r = 0.0f;
        if (lane < cnt) { s_r = ssrc[base + lane]; en_r = dinv[s_r] * di; }
        int j = 0;
        for (; j + 8 <= cnt; j += 8) {
            int sa = __shfl(s_r, j + sub);
            int sb = __shfl(s_r, j + 4 + sub);
            float ena = __shfl(en_r, j + sub);
            float enb = __shfl(en_r, j + 4 + sub);
            uint2 va = *reinterpret_cast<const uint2*>(hw + (((long)sa << 6) + (q << 2)));
            uint2 vb = *reinterpret_cast<const uint2*>(hw + (((long)sb << 6) + (q << 2)));
            ACC4(va, ena);
            ACC4(vb, enb);
        }
        for (; j < cnt; j += 4) {
            int e = j + sub;
            int s = __shfl(s_r, e);
            float en = __shfl(en_r, e);
            if (e >= cnt) { s = wid; en = 0.0f; }
            uint2 v = *reinterpret_cast<const uint2*>(hw + (((long)s << 6) + (q << 2)));
            ACC4(v, en);
        }
    }
    red4(acc);
    // self term + bias
    uint2 sv = *reinterpret_cast<const uint2*>(hw + (((long)wid << 6) + (q << 2)));
    float sn = di * di;
    float4 bq = *reinterpret_cast<const float4*>(b + (q << 2));
    acc.x += __uint_as_float((sv.x & 0xFFFFu) << 16) * sn + bq.x;
    acc.y += __uint_as_float(sv.x & 0xFFFF0000u) * sn + bq.y;
    acc.z += __uint_as_float((sv.y & 0xFFFFu) << 16) * sn + bq.z;
    acc.w += __uint_as_float(sv.y & 0xFFFF0000u) * sn + bq.w;
    return acc;
}

// Layer-1 fused: 16 nodes/block (4 per wave, gathered serially) -> relu ->
// bf16 H tile [16][72] in LDS -> hw2 tile = H @ W2 via 2x
// mfma_f32_16x16x32_bf16 per wave (wave wv owns feature tile f0=wv*16).
// W2 staged TRANSPOSED in LDS ([64][72] bf16) so B-fragments are contiguous
// ds_read_b128. Pad 72 keeps 16B alignment; row stride 144B -> 2-way bank
// aliasing only (free).
__global__ __launch_bounds__(256) void k_gather_mm(const bf16* __restrict__ hw,
                                                   const int* __restrict__ ssrc,
                                                   const int* __restrict__ off,
                                                   const float* __restrict__ dinv,
                                                   const float* __restrict__ b1,
                                                   const float* __restrict__ W2,
                                                   bf16* __restrict__ hw2, int N) {
    __shared__ __align__(16) bf16 W2t[64][72];  // [f][k], 9216B
    __shared__ __align__(16) bf16 H[16][72];    // [node][k], 2304B
    int tid = threadIdx.x;
    // stage W2 transposed: coalesced global read W2[k][f], scattered LDS write
    {
        int f = tid & 63;
        for (int k = tid >> 6; k < HID; k += 4)
            W2t[f][k] = __float2bfloat16(W2[k * 64 + f]);
    }
    __syncthreads();
    int wv = tid >> 6, lane = tid & 63;
    // gather 4 nodes per wave -> H rows
    for (int t = 0; t < 4; ++t) {
        int wid = blockIdx.x * 16 + wv * 4 + t;
        if (wid < N) {
            int j0 = off[wid], j1 = off[wid + 1];
            float di = dinv[wid];
            float4 r = gather_core(hw, ssrc, dinv, wid, j0, j1, di, lane, b1);
            if (lane < 16) {
                int row = wv * 4 + t, c = lane << 2;
                H[row][c + 0] = __float2bfloat16(fmaxf(r.x, 0.f));
                H[row][c + 1] = __float2bfloat16(fmaxf(r.y, 0.f));
                H[row][c + 2] = __float2bfloat16(fmaxf(r.z, 0.f));
                H[row][c + 3] = __float2bfloat16(fmaxf(r.w, 0.f));
            }
        }
    }
    __syncthreads();
    // MFMA: wave wv computes C tile [16 nodes][16 feats], f0 = wv*16.
    // A: row=lane&15, k=(lane>>4)*8+i ; B: col=lane&15, same k mapping.
    {
        int m = lane & 15;
        int kb = (lane >> 4) * 8;
        int f0 = wv * 16;
        bf16x8 a0 = *reinterpret_cast<const bf16x8*>(&H[m][kb]);
        bf16x8 a1 = *reinterpret_cast<const bf16x8*>(&H[m][kb + 32]);
        bf16x8 b0 = *reinterpret_cast<const bf16x8*>(&W2t[f0 + m][kb]);
        bf16x8 b1f = *reinterpret_cast<const bf16x8*>(&W2t[f0 + m][kb + 32]);
        f32x4 acc = {0.f, 0.f, 0.f, 0.f};
        acc = __builtin_amdgcn_mfma_f32_16x16x32_bf16(a0, b0, acc, 0, 0, 0);
        acc = __builtin_amdgcn_mfma_f32_16x16x32_bf16(a1, b1f, acc, 0, 0, 0);
#pragma unroll
        for (int rg = 0; rg < 4; ++rg) {
            int row = (lane >> 4) * 4 + rg;
            int nid = blockIdx.x * 16 + row;
            if (nid < N) hw2[((long)nid << 6) + f0 + m] = __float2bfloat16(acc[rg]);
        }
    }
}

// Layer-2 gather: agg2 (f32) out, relu deferred to pool.
__global__ __launch_bounds__(256) void k_gather4(const bf16* __restrict__ hw,
                                                 const int* __restrict__ ssrc,
                                                 const int* __restrict__ off,
                                                 const float* __restrict__ dinv,
                                                 const float* __restrict__ b,
                                                 float* __restrict__ outb, int N) {
    int wv = threadIdx.x >> 6, lane = threadIdx.x & 63;
    int wid = blockIdx.x * 4 + wv;
    if (wid >= N) return;
    int j0 = off[wid], j1 = off[wid + 1];
    float di = dinv[wid];
    float4 r = gather_core(hw, ssrc, dinv, wid, j0, j1, di, lane, b);
    if ((lane >> 4) == 0)
        *reinterpret_cast<float4*>(outb + (((long)wid << 6) + ((lane & 15) << 2))) = r;
}

// relu + mean-pool: batch is SORTED; each wave owns a contiguous node range,
// register-accumulates, flushes one atomicAdd per graph transition.
__global__ __launch_bounds__(256) void k_relu_pool(const float* __restrict__ agg,
                                                   const int* __restrict__ batch,
                                                   float* __restrict__ pooled,
                                                   float* __restrict__ counts,
                                                   int N, int rows_per_wave) {
    int wid = blockIdx.x * (blockDim.x >> 6) + (threadIdx.x >> 6);
    int lane = threadIdx.x & 63;
    int i0 = wid * rows_per_wave;
    if (i0 >= N) return;
    int i1 = min(i0 + rows_per_wave, N);
    int cur = batch[i0];
    float acc = 0.0f, cnt = 0.0f;
    for (int i = i0; i < i1; ++i) {
        int g = batch[i];
        if (g != cur) {
            atomicAdd(&pooled[cur * 64 + lane], acc);
            if (lane == 0) atomicAdd(&counts[cur], cnt);
            acc = 0.0f; cnt = 0.0f; cur = g;
        }
        acc += fmaxf(agg[(long)i * 64 + lane], 0.0f);
        cnt += 1.0f;
    }
    atomicAdd(&pooled[cur * 64 + lane], acc);
    if (lane == 0) atomicAdd(&counts[cur], cnt);
}

// mu / logvar heads with fused mean-divide -> out[900 + idx]
__global__ void k_heads(const float* __restrict__ pooled,
                        const float* __restrict__ counts,
                        const float* __restrict__ Wmu, const float* __restrict__ bmu,
                        const float* __restrict__ Wlv, const float* __restrict__ blv,
                        float* __restrict__ out) {
    int idx = blockIdx.x * blockDim.x + threadIdx.x;
    if (idx >= 2 * NG * LAT) return;
    int which = idx >> 11;          // 0: mu, 1: logvar
    int r = idx & (NG * LAT - 1);
    int g = r >> 5, l = r & 31;
    const float* W = which ? Wlv : Wmu;
    const float* b = which ? blv : bmu;
    float s = 0.0f;
#pragma unroll 8
    for (int h = 0; h < HID; ++h) s += pooled[g * 64 + h] * W[h * 32 + l];
    float c = fmaxf(counts[g], 1.0f);
    out[900 + idx] = s / c + b[l];
}

// Decoder stage 1: 30 blocks x 64 threads; parallelizes Wl2/We1 reads.
__global__ __launch_bounds__(64) void k_dec1(const float* __restrict__ Wl1,
                                             const float* __restrict__ bl1,
                                             const float* __restrict__ Wl2,
                                             const float* __restrict__ bl2,
                                             const float* __restrict__ We1,
                                             const float* __restrict__ out,
                                             float* __restrict__ hi,
                                             float* __restrict__ hj) {
    __shared__ float z0[LAT];
    __shared__ float hr[HID];
    __shared__ float em[HID];
    int tid = threadIdx.x;
    int n = blockIdx.x;
    if (tid < LAT) z0[tid] = out[900 + tid];  // mu row of graph 0
    __syncthreads();
    float s = bl1[tid];
#pragma unroll
    for (int l = 0; l < LAT; ++l) s += z0[l] * Wl1[l * HID + tid];
    hr[tid] = fmaxf(s, 0.0f);
    __syncthreads();
    float e = bl2[n * HID + tid];
#pragma unroll 8
    for (int h = 0; h < HID; ++h) e += hr[h] * Wl2[h * (HID * MAXN) + n * HID + tid];
    em[tid] = e;
    __syncthreads();
    float a = 0.0f, bb = 0.0f;
#pragma unroll 8
    for (int f = 0; f < HID; ++f) {
        float ev = em[f];
        a += ev * We1[f * HID + tid];
        bb += ev * We1[(HID + f) * HID + tid];
    }
    hi[n * HID + tid] = a;
    hj[n * HID + tid] = bb;
}

// Decoder stage 2: single block, adj from LDS-staged hi/hj (stride-65 pad).
__global__ __launch_bounds__(256) void k_dec2(const float* __restrict__ hi,
                                              const float* __restrict__ hj,
                                              const float* __restrict__ be1,
                                              const float* __restrict__ We2,
                                              const float* __restrict__ be2,
                                              float* __restrict__ out) {
    __shared__ float shi[MAXN * 65];
    __shared__ float shj[MAXN * 65];
    __shared__ float sbe[HID];
    __shared__ float sw[HID];
    int tid = threadIdx.x;
    for (int i = tid; i < MAXN * HID; i += 256) {
        int n = i >> 6, k = i & 63;
        shi[n * 65 + k] = hi[i];
        shj[n * 65 + k] = hj[i];
    }
    if (tid < HID) { sbe[tid] = be1[tid]; sw[tid] = We2[tid]; }
    __syncthreads();
    float bias2 = be2[0];
    for (int idx = tid; idx < MAXN * MAXN; idx += 256) {
        int i = idx / MAXN, j = idx % MAXN;
        if (i == j) { out[idx] = 0.0f; continue; }
        int a = i < j ? i : j;
        int b = i < j ? j : i;
        float s = bias2;
#pragma unroll 8
        for (int k = 0; k < HID; ++k)
            s += fmaxf(shi[a * 65 + k] + shj[b * 65 + k] + sbe[k], 0.0f) * sw[k];
        out[idx] = 1.0f / (1.0f + expf(-s));
    }
}

extern "C" void kernel_launch(void* const* d_in, const int* in_sizes, int n_in,
                              void* d_out, int out_size, void* d_ws, size_t ws_size,
                              hipStream_t stream) {
    const float* x = (const float*)d_in[0];
    const int* ei = (const int*)d_in[1];
    const int* batch = (const int*)d_in[2];
    const float* W1 = (const float*)d_in[4];
    const float* b1 = (const float*)d_in[5];
    const float* W2 = (const float*)d_in[6];
    const float* b2 = (const float*)d_in[7];
    const float* Wmu = (const float*)d_in[8];
    const float* bmu = (const float*)d_in[9];
    const float* Wlv = (const float*)d_in[10];
    const float* blv = (const float*)d_in[11];
    const float* Wl1 = (const float*)d_in[12];
    const float* bl1 = (const float*)d_in[13];
    const float* Wl2 = (const float*)d_in[14];
    const float* bl2 = (const float*)d_in[15];
    const float* We1 = (const float*)d_in[16];
    const float* be1 = (const float*)d_in[17];
    const float* We2 = (const float*)d_in[18];
    const float* be2 = (const float*)d_in[19];

    const int N = in_sizes[2];            // 50000
    const int E = in_sizes[1] / 2;        // 800000
    const int* src = ei;
    const int* dst = ei + E;

    // workspace carve-up, 256B aligned
    char* ws = (char*)d_ws;
    size_t off_b = 0;
    auto alloc = [&](size_t nbytes) {
        void* p = (void*)(ws + off_b);
        off_b = (off_b + nbytes + 255) & ~(size_t)255;
        return p;
    };
    float* dinv   = (float*)alloc((size_t)N * 4);
    float* bufA   = (float*)alloc((size_t)N * 64 * 4);        // agg2 (f32)
    bf16*  hwb1   = (bf16*)alloc((size_t)N * 64 * 2);         // hw1 (bf16)
    bf16*  hwb2   = (bf16*)alloc((size_t)N * 64 * 2);         // hw2 (bf16)
    // contiguous zero region: pooled | counts | hist
    float* pooled = (float*)alloc((NG * HID + NG + (size_t)N) * 4);
    float* counts = pooled + NG * HID;
    int*   hist   = (int*)(counts + NG);
    int*   incl   = (int*)alloc((size_t)N * 4);
    int*   bsum   = (int*)alloc(128 * 4);
    int*   offs   = (int*)alloc(((size_t)N + 1) * 4);
    int*   cursor = (int*)alloc((size_t)N * 4);
    int*   ssrc   = (int*)alloc((size_t)E * 4);
    float* dhi    = (float*)alloc(MAXN * HID * 4);
    float* dhj    = (float*)alloc(MAXN * HID * 4);

    float* out = (float*)d_out;
    const int nb_scan = (N + SCAN_CHUNK - 1) / SCAN_CHUNK;  // 98
    const int nzero = NG * HID + NG + N;

    // 0) one zero pass for pooled|counts|hist
    k_zero_w<<<(nzero + 255) / 256, 256, 0, stream>>>((int*)pooled, nzero);

    // 1) CSR build: hist -> scan -> offsets/dinv -> partitioned bucket fill
    k_hist_part<<<2048, 256, 0, stream>>>(dst, hist, N, E);
    k_scan1<<<nb_scan, SCAN_CHUNK, 0, stream>>>(hist, incl, bsum, N);
    k_scan_top<<<1, 128, 0, stream>>>(bsum, nb_scan);
    k_scan_add<<<(N + 255) / 256, 256, 0, stream>>>(hist, incl, bsum, offs, cursor, dinv, N, E);
    k_sortedges_part<<<1024, 256, 0, stream>>>(src, dst, cursor, ssrc, N, E);

    // 2) layer 1 GEMM: hw1 = bf16(x@W1)
    k_gemm<FEAT><<<2048, 256, 0, stream>>>(x, W1, hwb1, N);

    // 3) fused: gather1 + relu + MFMA gemm2 -> hw2 (16 nodes/block)
    k_gather_mm<<<(N + 15) / 16, 256, 0, stream>>>(hwb1, ssrc, offs, dinv, b1, W2, hwb2, N);

    // 4) gather2 -> agg2 (f32), relu deferred to pool
    k_gather4<<<(N + 3) / 4, 256, 0, stream>>>(hwb2, ssrc, offs, dinv, b2, bufA, N);

    // 5) relu + mean-pool (contiguous ranges, register accumulation)
    {
        const int waves = 2048;
        int rpw = (N + waves - 1) / waves;
        k_relu_pool<<<512, 256, 0, stream>>>(bufA, batch, pooled, counts, N, rpw);
    }

    // 6) mu / logvar (fused mean-divide) -> out[900:]
    k_heads<<<(2 * NG * LAT + 255) / 256, 256, 0, stream>>>(pooled, counts, Wmu, bmu, Wlv, blv, out);

    // 7) decoder -> out[0:900]
    k_dec1<<<MAXN, 64, 0, stream>>>(Wl1, bl1, Wl2, bl2, We1, out, dhi, dhj);
    k_dec2<<<1, 256, 0, stream>>>(dhi, dhj, be1, We2, be2, out);
}